// Round 9
// baseline (351.419 us; speedup 1.0000x reference)
//
#include <hip/hip_runtime.h>
#include <cstddef>

#define D_MODEL 1024
#define D_STATE 16
#define DT_RANK 64
#define BATCH 4
#define SEQ 4096
#define NPROJ 96                 // DT_RANK + 2*D_STATE
#define M_TOTAL (BATCH * SEQ)    // 16384
#define NCHUNK 128
#define CLEN 32                  // SEQ / NCHUNK
#define KSPLIT 4
#define KSLICE 256               // 1024 / KSPLIT

typedef __attribute__((ext_vector_type(8))) short bf16x8;
typedef __attribute__((ext_vector_type(4))) short short4v;
typedef __attribute__((ext_vector_type(4))) float f32x4;

__device__ __forceinline__ float softplus_fast(float v) {
    return fmaxf(v, 0.0f) + __logf(1.0f + __expf(-fabsf(v)));
}

// float -> bf16 (RNE), and back
__device__ __forceinline__ short f2bf(float x) {
    union { float f; unsigned u; } v; v.f = x;
    unsigned r = (v.u + 0x7fffu + ((v.u >> 16) & 1u)) >> 16;
    return (short)r;
}
__device__ __forceinline__ float bf2f(short s) {
    union { unsigned u; float f; } v; v.u = ((unsigned)(unsigned short)s) << 16;
    return v.f;
}
struct bfpair { short hi, lo; };
__device__ __forceinline__ bfpair split_bf(float x) {
    bfpair r;
    r.hi = f2bf(x);
    r.lo = f2bf(x - bf2f(r.hi));
    return r;
}
__device__ __forceinline__ void split_bf4(float4 v, short4v& h, short4v& l) {
    bfpair a = split_bf(v.x), b = split_bf(v.y), c = split_bf(v.z), d = split_bf(v.w);
    h = (short4v){a.hi, b.hi, c.hi, d.hi};
    l = (short4v){a.lo, b.lo, c.lo, d.lo};
}

// ---------------- GEMM1 (split-K, MFMA hi/lo): part[ks][m,p] ----------------
__global__ __launch_bounds__(256) void proj_mfma_kernel(const float* __restrict__ x,
                                                        const float* __restrict__ W,
                                                        float* __restrict__ part) {
    __shared__ short ah[64][40], al[64][40];
    __shared__ short bh[96][40], bl[96][40];
    const int tid   = threadIdx.x;
    const int row0  = blockIdx.x * 64;
    const int kbase = blockIdx.y * KSLICE;
    const int wid   = tid >> 6;
    const int lane  = tid & 63;
    const int l16   = lane & 15;
    const int kg    = lane >> 4;

    f32x4 acc[6];
#pragma unroll
    for (int c = 0; c < 6; ++c) acc[c] = (f32x4){0.f, 0.f, 0.f, 0.f};

    for (int k0 = kbase; k0 < kbase + KSLICE; k0 += 32) {
        for (int i = tid; i < 64 * 8; i += 256) {
            int r = i >> 3, c4 = i & 7;
            float4 v = *reinterpret_cast<const float4*>(
                &x[(size_t)(row0 + r) * 1024 + k0 + c4 * 4]);
            short4v h, l;
            split_bf4(v, h, l);
            *reinterpret_cast<short4v*>(&ah[r][c4 * 4]) = h;
            *reinterpret_cast<short4v*>(&al[r][c4 * 4]) = l;
        }
        for (int i = tid; i < 96 * 8; i += 256) {
            int r = i >> 3, c4 = i & 7;
            float4 v = *reinterpret_cast<const float4*>(
                &W[(size_t)r * 1024 + k0 + c4 * 4]);
            short4v h, l;
            split_bf4(v, h, l);
            *reinterpret_cast<short4v*>(&bh[r][c4 * 4]) = h;
            *reinterpret_cast<short4v*>(&bl[r][c4 * 4]) = l;
        }
        __syncthreads();

        bf16x8 a_h = *reinterpret_cast<const bf16x8*>(&ah[wid * 16 + l16][kg * 8]);
        bf16x8 a_l = *reinterpret_cast<const bf16x8*>(&al[wid * 16 + l16][kg * 8]);
#pragma unroll
        for (int c = 0; c < 6; ++c) {
            bf16x8 b_h = *reinterpret_cast<const bf16x8*>(&bh[c * 16 + l16][kg * 8]);
            bf16x8 b_l = *reinterpret_cast<const bf16x8*>(&bl[c * 16 + l16][kg * 8]);
            acc[c] = __builtin_amdgcn_mfma_f32_16x16x32_bf16(a_h, b_h, acc[c], 0, 0, 0);
            acc[c] = __builtin_amdgcn_mfma_f32_16x16x32_bf16(a_h, b_l, acc[c], 0, 0, 0);
            acc[c] = __builtin_amdgcn_mfma_f32_16x16x32_bf16(a_l, b_h, acc[c], 0, 0, 0);
        }
        __syncthreads();
    }
    size_t base = ((size_t)blockIdx.y * M_TOTAL + row0 + wid * 16 + kg * 4) * NPROJ;
#pragma unroll
    for (int c = 0; c < 6; ++c) {
#pragma unroll
        for (int q = 0; q < 4; ++q)
            part[base + (size_t)q * NPROJ + c * 16 + l16] = acc[c][q];
    }
}

// ---------------- reduce: xp = sum_ks part[ks] ----------------
__global__ __launch_bounds__(256) void reduce_xp_kernel(const float* __restrict__ part,
                                                        float* __restrict__ xp) {
    const size_t stride4 = (size_t)M_TOTAL * NPROJ / 4;
    size_t i = (size_t)blockIdx.x * 256 + threadIdx.x;
    const float4* p = reinterpret_cast<const float4*>(part);
    float4 a = p[i];
#pragma unroll
    for (int s = 1; s < KSPLIT; ++s) {
        float4 b = p[i + (size_t)s * stride4];
        a.x += b.x; a.y += b.y; a.z += b.z; a.w += b.w;
    }
    reinterpret_cast<float4*>(xp)[i] = a;
}

// ------- GEMM2 (MFMA hi/lo): delta = softplus(xp[:, :64]*Wd^T + b) -----
__global__ __launch_bounds__(256) void delta_mfma_kernel(const float* __restrict__ xp,
                                                         const float* __restrict__ Wd,
                                                         const float* __restrict__ b_dt,
                                                         float* __restrict__ delta) {
    __shared__ short ah[64][72], al[64][72];
    __shared__ short bh[64][72], bl[64][72];
    const int tid  = threadIdx.x;
    const int row0 = blockIdx.x * 64;
    const int col0 = blockIdx.y * 64;
    const int wid  = tid >> 6;
    const int lane = tid & 63;
    const int l16  = lane & 15;
    const int kg   = lane >> 4;

    for (int i = tid; i < 64 * 16; i += 256) {
        int r = i >> 4, c4 = i & 15;
        float4 v = *reinterpret_cast<const float4*>(
            &xp[(size_t)(row0 + r) * NPROJ + c4 * 4]);
        short4v h, l;
        split_bf4(v, h, l);
        *reinterpret_cast<short4v*>(&ah[r][c4 * 4]) = h;
        *reinterpret_cast<short4v*>(&al[r][c4 * 4]) = l;
    }
    for (int i = tid; i < 64 * 16; i += 256) {
        int r = i >> 4, c4 = i & 15;
        float4 v = *reinterpret_cast<const float4*>(
            &Wd[(size_t)(col0 + r) * 64 + c4 * 4]);
        short4v h, l;
        split_bf4(v, h, l);
        *reinterpret_cast<short4v*>(&bh[r][c4 * 4]) = h;
        *reinterpret_cast<short4v*>(&bl[r][c4 * 4]) = l;
    }
    __syncthreads();

    f32x4 acc[4];
#pragma unroll
    for (int j = 0; j < 4; ++j) acc[j] = (f32x4){0.f, 0.f, 0.f, 0.f};

#pragma unroll
    for (int ks = 0; ks < 2; ++ks) {
        int koff = ks * 32 + kg * 8;
        bf16x8 a_h = *reinterpret_cast<const bf16x8*>(&ah[wid * 16 + l16][koff]);
        bf16x8 a_l = *reinterpret_cast<const bf16x8*>(&al[wid * 16 + l16][koff]);
#pragma unroll
        for (int j = 0; j < 4; ++j) {
            bf16x8 b_h = *reinterpret_cast<const bf16x8*>(&bh[j * 16 + l16][koff]);
            bf16x8 b_l = *reinterpret_cast<const bf16x8*>(&bl[j * 16 + l16][koff]);
            acc[j] = __builtin_amdgcn_mfma_f32_16x16x32_bf16(a_h, b_h, acc[j], 0, 0, 0);
            acc[j] = __builtin_amdgcn_mfma_f32_16x16x32_bf16(a_h, b_l, acc[j], 0, 0, 0);
            acc[j] = __builtin_amdgcn_mfma_f32_16x16x32_bf16(a_l, b_h, acc[j], 0, 0, 0);
        }
    }

    int row = row0 + wid * 16 + kg * 4;
#pragma unroll
    for (int j = 0; j < 4; ++j) {
        int col = col0 + j * 16 + l16;
        float bias = b_dt[col];
#pragma unroll
        for (int q = 0; q < 4; ++q)
            delta[(size_t)(row + q) * D_MODEL + col] = softplus_fast(acc[j][q] + bias);
    }
}

// ---------------- Scan pass A: per-chunk transfer; B staged in LDS ----------
// grid (NCHUNK, 4, BATCH), 256 thr. Per-chunk B rows (block-uniform) staged
// once; inner reads are same-address broadcasts (conflict-free).
__global__ __launch_bounds__(256) void scanA_kernel(const float* __restrict__ x,
                                                    const float* __restrict__ xp,
                                                    const float* __restrict__ delta,
                                                    const float* __restrict__ A_log,
                                                    float* __restrict__ P,
                                                    float* __restrict__ H) {
    __shared__ float Bs[CLEN][16];
    const int chunk = blockIdx.x;
    const int b     = blockIdx.z;
    const int tid   = threadIdx.x;
    const int d     = blockIdx.y * 256 + tid;
    const float LOG2E = 1.4426950408889634f;

    const size_t m0 = (size_t)b * SEQ + (size_t)chunk * CLEN;
    // stage B: CLEN*16 floats = CLEN*4 float4 (threads 0..CLEN*4-1)
    if (tid < CLEN * 4) {
        int j = tid >> 2, q = tid & 3;
        float4 v = *reinterpret_cast<const float4*>(
            xp + (m0 + j) * NPROJ + DT_RANK + q * 4);
        *reinterpret_cast<float4*>(&Bs[j][q * 4]) = v;
    }

    float Av[16];
    const float4* Arow = reinterpret_cast<const float4*>(A_log + (size_t)d * D_STATE);
#pragma unroll
    for (int q = 0; q < 4; ++q) {
        float4 v = Arow[q];
        Av[q*4+0] = -__expf(v.x) * LOG2E; Av[q*4+1] = -__expf(v.y) * LOG2E;
        Av[q*4+2] = -__expf(v.z) * LOG2E; Av[q*4+3] = -__expf(v.w) * LOG2E;
    }
    float h[16];
#pragma unroll
    for (int n = 0; n < 16; ++n) h[n] = 0.0f;
    float sdv = 0.0f;

    const size_t xbase = m0 * D_MODEL + d;
    __syncthreads();

#pragma unroll 4
    for (int j = 0; j < CLEN; ++j) {
        float dv = delta[xbase + (size_t)j * D_MODEL];
        float xv = x[xbase + (size_t)j * D_MODEL];
        float dtx = dv * xv;
        sdv += dv;
#pragma unroll
        for (int g = 0; g < 4; ++g) {
            float4 Bq = *reinterpret_cast<const float4*>(&Bs[j][g * 4]);
            h[g*4+0] = fmaf(exp2f(dv * Av[g*4+0]), h[g*4+0], dtx * Bq.x);
            h[g*4+1] = fmaf(exp2f(dv * Av[g*4+1]), h[g*4+1], dtx * Bq.y);
            h[g*4+2] = fmaf(exp2f(dv * Av[g*4+2]), h[g*4+2], dtx * Bq.z);
            h[g*4+3] = fmaf(exp2f(dv * Av[g*4+3]), h[g*4+3], dtx * Bq.w);
        }
    }
    size_t idx = (((size_t)chunk * BATCH + b) * D_MODEL + d) * D_STATE;
    float4* Pp = reinterpret_cast<float4*>(P + idx);
    float4* Hp = reinterpret_cast<float4*>(H + idx);
#pragma unroll
    for (int q = 0; q < 4; ++q) {
        float4 pv, hv;
        pv.x = exp2f(Av[q*4+0] * sdv); pv.y = exp2f(Av[q*4+1] * sdv);
        pv.z = exp2f(Av[q*4+2] * sdv); pv.w = exp2f(Av[q*4+3] * sdv);
        hv.x = h[q*4+0]; hv.y = h[q*4+1]; hv.z = h[q*4+2]; hv.w = h[q*4+3];
        Pp[q] = pv; Hp[q] = hv;
    }
}

// ---------------- Scan pass B: inter-chunk scan; rewrites P <- carry-in ----
__global__ __launch_bounds__(256) void scanB_kernel(float* __restrict__ P,
                                                    const float* __restrict__ H) {
    const int t = blockIdx.x * 256 + threadIdx.x;
    float carry = 0.0f;
    for (int c = 0; c < NCHUNK; ++c) {
        size_t idx = (size_t)c * (BATCH * D_MODEL * D_STATE) + t;
        float p  = P[idx];
        float hh = H[idx];
        P[idx] = carry;
        carry = fmaf(p, carry, hh);
    }
}

// ---------------- Scan pass C: replay with carry-in; B,C staged in LDS ------
__global__ __launch_bounds__(256) void scanC_kernel(const float* __restrict__ x,
                                                    const float* __restrict__ xp,
                                                    const float* __restrict__ delta,
                                                    const float* __restrict__ A_log,
                                                    const float* __restrict__ Dvec,
                                                    const float* __restrict__ Hin,
                                                    float* __restrict__ out) {
    __shared__ float BCs[CLEN][32];   // [j][0..15]=B, [j][16..31]=C
    const int chunk = blockIdx.x;
    const int b     = blockIdx.z;
    const int tid   = threadIdx.x;
    const int d     = blockIdx.y * 256 + tid;
    const float LOG2E = 1.4426950408889634f;

    const size_t m0 = (size_t)b * SEQ + (size_t)chunk * CLEN;
    // stage B+C: CLEN*32 floats = CLEN*8 float4 (256 threads, 1 each)
    {
        int j = tid >> 3, q = tid & 7;
        float4 v = *reinterpret_cast<const float4*>(
            xp + (m0 + j) * NPROJ + DT_RANK + q * 4);
        *reinterpret_cast<float4*>(&BCs[j][q * 4]) = v;
    }

    float Av[16];
    const float4* Arow = reinterpret_cast<const float4*>(A_log + (size_t)d * D_STATE);
#pragma unroll
    for (int q = 0; q < 4; ++q) {
        float4 v = Arow[q];
        Av[q*4+0] = -__expf(v.x) * LOG2E; Av[q*4+1] = -__expf(v.y) * LOG2E;
        Av[q*4+2] = -__expf(v.z) * LOG2E; Av[q*4+3] = -__expf(v.w) * LOG2E;
    }
    const float Dv = Dvec[d];

    float h[16];
    size_t idx = (((size_t)chunk * BATCH + b) * D_MODEL + d) * D_STATE;
    const float4* Hp = reinterpret_cast<const float4*>(Hin + idx);
#pragma unroll
    for (int q = 0; q < 4; ++q) {
        float4 v = Hp[q];
        h[q*4+0] = v.x; h[q*4+1] = v.y; h[q*4+2] = v.z; h[q*4+3] = v.w;
    }

    const size_t xbase = m0 * D_MODEL + d;
    __syncthreads();

#pragma unroll 4
    for (int j = 0; j < CLEN; ++j) {
        float dv = delta[xbase + (size_t)j * D_MODEL];
        float xv = x[xbase + (size_t)j * D_MODEL];
        float dtx = dv * xv;
        float y0 = 0.f, y1 = 0.f, y2 = 0.f, y3 = 0.f;
#pragma unroll
        for (int g = 0; g < 4; ++g) {
            float4 Bq = *reinterpret_cast<const float4*>(&BCs[j][g * 4]);
            float4 Cq = *reinterpret_cast<const float4*>(&BCs[j][16 + g * 4]);
            float h0 = fmaf(exp2f(dv * Av[g*4+0]), h[g*4+0], dtx * Bq.x);
            float h1 = fmaf(exp2f(dv * Av[g*4+1]), h[g*4+1], dtx * Bq.y);
            float h2 = fmaf(exp2f(dv * Av[g*4+2]), h[g*4+2], dtx * Bq.z);
            float h3 = fmaf(exp2f(dv * Av[g*4+3]), h[g*4+3], dtx * Bq.w);
            h[g*4+0] = h0; h[g*4+1] = h1; h[g*4+2] = h2; h[g*4+3] = h3;
            y0 = fmaf(h0, Cq.x, y0);
            y1 = fmaf(h1, Cq.y, y1);
            y2 = fmaf(h2, Cq.z, y2);
            y3 = fmaf(h3, Cq.w, y3);
        }
        float y = (y0 + y1) + (y2 + y3);
        out[xbase + (size_t)j * D_MODEL] = fmaf(xv, Dv, y);
    }
}

extern "C" void kernel_launch(void* const* d_in, const int* in_sizes, int n_in,
                              void* d_out, int out_size, void* d_ws, size_t ws_size,
                              hipStream_t stream) {
    const float* x    = (const float*)d_in[0];
    const float* Wx   = (const float*)d_in[1];
    const float* Wd   = (const float*)d_in[2];
    const float* bdt  = (const float*)d_in[3];
    const float* Alog = (const float*)d_in[4];
    const float* Dv   = (const float*)d_in[5];
    float* out = (float*)d_out;

    float* ws    = (float*)d_ws;
    float* xp    = ws;                                        // 6.3 MB
    float* delta = xp + (size_t)M_TOTAL * NPROJ;              // 67.1 MB
    float* scan0 = delta + (size_t)M_TOTAL * D_MODEL;
    float* part  = scan0;   // 25.2 MB, dead before P/H written
    float* P     = scan0;                                     // 33.55 MB
    float* H     = scan0 + (size_t)NCHUNK * BATCH * D_MODEL * D_STATE;

    proj_mfma_kernel<<<dim3(M_TOTAL / 64, KSPLIT), 256, 0, stream>>>(x, Wx, part);
    reduce_xp_kernel<<<dim3((M_TOTAL * NPROJ / 4) / 256), 256, 0, stream>>>(part, xp);
    delta_mfma_kernel<<<dim3(M_TOTAL / 64, D_MODEL / 64), 256, 0, stream>>>(xp, Wd, bdt, delta);
    scanA_kernel<<<dim3(NCHUNK, 4, BATCH), 256, 0, stream>>>(x, xp, delta, Alog, P, H);
    scanB_kernel<<<dim3((BATCH * D_MODEL * D_STATE) / 256), 256, 0, stream>>>(P, H);
    scanC_kernel<<<dim3(NCHUNK, 4, BATCH), 256, 0, stream>>>(x, xp, delta, Alog, Dv, P, out);
}